// Round 12
// baseline (148.079 us; speedup 1.0000x reference)
//
#include <hip/hip_runtime.h>
#include <cstdint>

#define B_   16
#define T_   2048
#define CIN  96
#define DH   64
#define NOUT 128

typedef float floatx4 __attribute__((ext_vector_type(4)));
typedef short shortx8 __attribute__((ext_vector_type(8)));
typedef unsigned int uintx2 __attribute__((ext_vector_type(2)));

__device__ __forceinline__ unsigned short f2bf(float f) {
  unsigned int u = __float_as_uint(f);
  u += 0x7FFFu + ((u >> 16) & 1u);           // RTNE
  return (unsigned short)(u >> 16);
}
// packed f32x2 -> bf16x2 (RTNE) in one VALU op
__device__ __forceinline__ uint32_t cvtpk(float lo, float hi) {
  uint32_t r;
  asm("v_cvt_pk_bf16_f32 %0, %1, %2" : "=v"(r) : "v"(lo), "v"(hi));
  return r;
}
__device__ __forceinline__ floatx4 f4zero() { floatx4 v; v[0]=0.f;v[1]=0.f;v[2]=0.f;v[3]=0.f; return v; }
__device__ __forceinline__ shortx8 s8zero() { shortx8 v;
#pragma unroll
  for (int i=0;i<8;++i) v[i]=0; return v; }

// swap32 then swap16 between two dwords: redistributes swapped-QK^T P rows
// into the PV A-fragment layout (see k_attn).
__device__ __forceinline__ void plane_swap(uint32_t& a, uint32_t& b) {
#if __has_builtin(__builtin_amdgcn_permlane32_swap) && __has_builtin(__builtin_amdgcn_permlane16_swap)
  uintx2 r1 = __builtin_amdgcn_permlane32_swap(a, b, false, false);
  uintx2 r2 = __builtin_amdgcn_permlane16_swap(r1[0], r1[1], false, false);
  a = r2[0]; b = r2[1];
#else
  asm volatile("v_permlane32_swap_b32 %0, %1\n\t"
               "v_permlane16_swap_b32 %0, %1"
               : "+v"(a), "+v"(b));
#endif
}

// ---------------- k0: weight prep (bf16 + transpose) ----------------
__global__ __launch_bounds__(256) void k_wprep(
    const float* __restrict__ qkv_w, const float* __restrict__ cw1,
    const float* __restrict__ cw2, const float* __restrict__ dw,
    unsigned short* __restrict__ qwt, unsigned short* __restrict__ w1t,
    unsigned short* __restrict__ w2t, unsigned short* __restrict__ dwt)
{
  int o = blockIdx.x * 256 + threadIdx.x;
  if (o < 18432) {
    int co = o / 96, ci = o % 96;
    qwt[o] = f2bf(qkv_w[ci * 192 + co]);
  } else if (o < 43008) {
    int p = o - 18432;
    int tap = p / 8192, rem = p % 8192, co = rem >> 6, ci = rem & 63;
    w1t[p] = f2bf(cw1[(tap * 64 + ci) * 128 + co]);
  } else if (o < 92160) {
    int p = o - 43008;
    int tap = p / 16384, rem = p % 16384, co = rem >> 7, ci = rem & 127;
    w2t[p] = f2bf(cw2[(tap * 128 + ci) * 128 + co]);
  } else if (o < 104448) {
    int p = o - 92160;
    int co = p / 96, ci = p % 96;
    dwt[p] = f2bf(dw[ci * 128 + co]);
  }
}

// ---------------- k1: qkv projection; q pre-scaled by scale*log2(e) ----------------
// 32-row tiles, 1024 blocks -> 4 blocks/CU (was 2): doubles waves/SIMD for
// latency hiding. Per-element math identical. V epilogue routes through LDS
// (Vs) so vT stores are coalesced 64B segments.
__global__ __launch_bounds__(256) void k_qkv(
    const float* __restrict__ x, const unsigned short* __restrict__ qwt,
    const float* __restrict__ qkv_b, const float* __restrict__ scale_p,
    unsigned short* __restrict__ qb, unsigned short* __restrict__ kb,
    unsigned short* __restrict__ vT)
{
  __shared__ __align__(16) unsigned short Xs[32][104];
  __shared__ __align__(16) unsigned short Vs[64][40];   // [d][t_local]
  const int bx = blockIdx.x;
  const int b = bx >> 6, t0 = (bx & 63) * 32;
  const int tid = threadIdx.x, wave = tid >> 6, lane = tid & 63;
  const int l15 = lane & 15, quad = lane >> 4;
  const float scl2 = scale_p[0] * 1.4426950408889634f;

  for (int idx = tid; idx < 32 * 24; idx += 256) {
    int r = idx / 24, c = (idx % 24) * 4;
    float4 xv = *(const float4*)(x + ((size_t)(b * T_ + t0 + r)) * CIN + c);
    ushort4 o; o.x = f2bf(xv.x); o.y = f2bf(xv.y); o.z = f2bf(xv.z); o.w = f2bf(xv.w);
    *(ushort4*)(&Xs[r][c]) = o;
  }
  __syncthreads();

  floatx4 acc[2][3];
#pragma unroll
  for (int mt = 0; mt < 2; ++mt)
#pragma unroll
    for (int nt = 0; nt < 3; ++nt) acc[mt][nt] = f4zero();

#pragma unroll
  for (int ks = 0; ks < 3; ++ks) {
    shortx8 wf[3];
#pragma unroll
    for (int nt = 0; nt < 3; ++nt) {
      int j = wave * 48 + nt * 16 + l15;
      wf[nt] = *(const shortx8*)(qwt + (size_t)j * 96 + ks * 32 + quad * 8);
    }
#pragma unroll
    for (int mt = 0; mt < 2; ++mt) {
      shortx8 af = *(const shortx8*)(&Xs[mt * 16 + l15][ks * 32 + quad * 8]);
#pragma unroll
      for (int nt = 0; nt < 3; ++nt)
        acc[mt][nt] = __builtin_amdgcn_mfma_f32_16x16x32_bf16(af, wf[nt], acc[mt][nt], 0, 0, 0);
    }
  }

#pragma unroll
  for (int nt = 0; nt < 3; ++nt) {
    int j0 = wave * 48 + nt * 16;
    int j = j0 + l15;
    float bias = qkv_b[j];
#pragma unroll
    for (int mt = 0; mt < 2; ++mt) {
#pragma unroll
      for (int r = 0; r < 4; ++r) {
        int t = t0 + mt * 16 + quad * 4 + r;
        float v = acc[mt][nt][r] + bias;
        if (j0 < 64)        qb[((size_t)b * T_ + t) * DH + j] = f2bf(v * scl2);
        else if (j0 < 128)  kb[((size_t)b * T_ + t) * DH + (j - 64)] = f2bf(v);
        else                Vs[j - 128][mt * 16 + quad * 4 + r] = f2bf(v);
      }
    }
  }
  __syncthreads();
  // coalesced vT write: row d gets 32 consecutive t (64B) via 4 x 16B lanes
  for (int idx = tid; idx < 64 * 4; idx += 256) {
    int d = idx >> 2, seg = (idx & 3) * 8;
    *(shortx8*)(vT + ((size_t)b * DH + d) * T_ + t0 + seg) =
        *(const shortx8*)(&Vs[d][seg]);
  }
}

// ---------------- k2: streaming attention, no-max softmax, full-S ----------------
// 4 waves x 16 queries, one block covers all 32 K/V tiles (no split-S): the
// row-sum (ones-column in V via MFMA) completes in-kernel, so O is normalized
// in registers and written as bf16 ab directly — no fp32 partial round-trip.
// Swapped QK^T keeps P lane-local; v_cvt_pk_bf16_f32 + permlane32/16_swap
// redistribute P to the PV A-fragment with no LDS and minimal VALU.
__global__ __launch_bounds__(256) void k_attn(
    const unsigned short* __restrict__ qb, const unsigned short* __restrict__ kb,
    const unsigned short* __restrict__ vT,
    unsigned short* __restrict__ ab)
{
  __shared__ __align__(16) unsigned short Kt[64][72];    // [s][d]
  __shared__ __align__(16) unsigned short Vt[80][72];    // [d][s]; rows 64..79: ones/zeros
  const int bx = blockIdx.x;
  const int qt = bx & 31, b = bx >> 5;
  const int tid = threadIdx.x, wave = tid >> 6, lane = tid & 63;
  const int l15 = lane & 15, quad = lane >> 4;

  const unsigned short* qrow = qb + ((size_t)b * T_ + qt * 64 + wave * 16 + l15) * DH;
  shortx8 qf0 = *(const shortx8*)(qrow + quad * 8);
  shortx8 qf1 = *(const shortx8*)(qrow + 32 + quad * 8);

  floatx4 O[5];
#pragma unroll
  for (int i = 0; i < 5; ++i) O[i] = f4zero();

  const unsigned short* kbase = kb + (size_t)b * T_ * DH;
  const unsigned short* vbase = vT + (size_t)b * DH * T_;

  // ones-column rows of Vt (d=64 -> 1.0, d=65..79 -> 0), written once
  for (int idx = tid; idx < 16 * 72; idx += 256) {
    int r = idx / 72, c = idx % 72;
    Vt[64 + r][c] = (r == 0) ? (unsigned short)0x3F80 : (unsigned short)0;
  }

  const int kr0 = tid >> 3, kc = (tid & 7) * 8;          // staging coords
  shortx8 pk[2], pv[2];
#pragma unroll
  for (int i = 0; i < 2; ++i) {                          // prefetch tile 0
    pk[i] = *(const shortx8*)(kbase + (size_t)(kr0 + i * 32) * DH + kc);
    pv[i] = *(const shortx8*)(vbase + (size_t)(kr0 + i * 32) * T_ + kc);
  }

  for (int t = 0; t < 32; ++t) {
#pragma unroll
    for (int i = 0; i < 2; ++i) {                        // regs -> LDS
      *(shortx8*)(&Kt[kr0 + i * 32][kc]) = pk[i];
      *(shortx8*)(&Vt[kr0 + i * 32][kc]) = pv[i];
    }
    __syncthreads();                                     // tiles (and ones rows) visible

    if (t < 31) {                                        // prefetch next tile
      int s0 = (t + 1) * 64;
#pragma unroll
      for (int i = 0; i < 2; ++i) {
        pk[i] = *(const shortx8*)(kbase + (size_t)(s0 + kr0 + i * 32) * DH + kc);
        pv[i] = *(const shortx8*)(vbase + (size_t)(kr0 + i * 32) * T_ + s0 + kc);
      }
    }

    // S^T = K.q^T: lane holds S[key=nt*16+quad*4+r][query=l15]
    floatx4 S[4];
#pragma unroll
    for (int nt = 0; nt < 4; ++nt) {
      shortx8 bk0 = *(const shortx8*)(&Kt[nt * 16 + l15][quad * 8]);
      shortx8 bk1 = *(const shortx8*)(&Kt[nt * 16 + l15][32 + quad * 8]);
      S[nt] = f4zero();
      S[nt] = __builtin_amdgcn_mfma_f32_16x16x32_bf16(bk0, qf0, S[nt], 0, 0, 0);
      S[nt] = __builtin_amdgcn_mfma_f32_16x16x32_bf16(bk1, qf1, S[nt], 0, 0, 0);
    }

    // P = exp2(S^T), packed to bf16 pairs via v_cvt_pk_bf16_f32
    uint32_t pkv[8];
#pragma unroll
    for (int nt = 0; nt < 4; ++nt) {
#pragma unroll
      for (int j = 0; j < 2; ++j)
        pkv[nt * 2 + j] = cvtpk(exp2f(S[nt][2 * j]), exp2f(S[nt][2 * j + 1]));
    }

    // Redistribute to PV A-fragment: lane quad q needs keys 32*kk+8q..+7 of
    // query l15. swap32 then swap16 on (ntl=0, ntl=1) reg pairs yields exactly
    // A-frag dwords i=j (from a) and i=j+2 (from b).
#pragma unroll
    for (int kk = 0; kk < 2; ++kk) {
      uint32_t a0 = pkv[4 * kk + 0], b0 = pkv[4 * kk + 2];   // j=0
      plane_swap(a0, b0);
      uint32_t a1 = pkv[4 * kk + 1], b1 = pkv[4 * kk + 3];   // j=1
      plane_swap(a1, b1);
      union { shortx8 s; uint32_t u[4]; } fu;
      fu.u[0] = a0; fu.u[1] = a1; fu.u[2] = b0; fu.u[3] = b1;
#pragma unroll
      for (int dt = 0; dt < 5; ++dt) {
        shortx8 bv = *(const shortx8*)(&Vt[dt * 16 + l15][kk * 32 + quad * 8]);
        O[dt] = __builtin_amdgcn_mfma_f32_16x16x32_bf16(fu.s, bv, O[dt], 0, 0, 0);
      }
    }
    __syncthreads();                                     // K/V consumed before restage
  }

  // normalize in-register and store bf16: lanes l15==0 hold row-sums (col 64)
  unsigned short* abase = ab + ((size_t)b * T_ + qt * 64 + wave * 16) * DH;
#pragma unroll
  for (int r = 0; r < 4; ++r) {
    float s = __shfl(O[4][r], quad << 4);
    float inv = 1.f / s;
    int row = quad * 4 + r;
#pragma unroll
    for (int dt = 0; dt < 4; ++dt)
      abase[(size_t)row * DH + dt * 16 + l15] = f2bf(O[dt][r] * inv);
  }
}

// ---------------- k3: FUSED conv1+relu -> (LDS) -> conv2+relu+residual+relu ----------------
// 32-output-row tiles, 1024 blocks -> 4 blocks/CU (was 2). conv1 is computed
// locally for 48 rows (hr=0..47 <-> t=t0-8+hr, 3 MFMA row-tiles) from a
// 50-row At halo stage, rounded through f2bf into LDS Ht — bit-identical to
// the old hb path. Rows with global t outside [0,T) are ZEROED in Ht (conv2
// 'same' padding needs h=0 there). Then conv2 + downsample residual.
__global__ __launch_bounds__(256) void k_conv12(
    const unsigned short* __restrict__ ab, const float* __restrict__ x,
    const unsigned short* __restrict__ w1t, const unsigned short* __restrict__ w2t,
    const unsigned short* __restrict__ dwt,
    const float* __restrict__ b1, const float* __restrict__ b2,
    float* __restrict__ out)
{
  __shared__ __align__(16) unsigned short At[50][72];    // a rows t0-9 .. t0+40
  __shared__ __align__(16) unsigned short Ht[48][136];   // h rows t0-8 .. t0+39
  __shared__ __align__(16) unsigned short Xt[32][104];
  const int bx = blockIdx.x;
  const int b = bx >> 6, t0 = (bx & 63) * 32;
  const int tid = threadIdx.x, wave = tid >> 6, lane = tid & 63;
  const int l15 = lane & 15, quad = lane >> 4;

  // stage ab with halo: At[ar] <-> t = t0-9+ar
  for (int idx = tid; idx < 50 * 8; idx += 256) {
    int r = idx >> 3, c = (idx & 7) * 8;
    int t = t0 + r - 9;
    shortx8 v = s8zero();
    if (t >= 0 && t < T_) v = *(const shortx8*)(ab + ((size_t)b * T_ + t) * DH + c);
    *(shortx8*)(&At[r][c]) = v;
  }
  // stage x for the residual path
  for (int idx = tid; idx < 32 * 24; idx += 256) {
    int r = idx / 24, c = (idx % 24) * 4;
    float4 xv = *(const float4*)(x + ((size_t)(b * T_ + t0 + r)) * CIN + c);
    ushort4 o; o.x = f2bf(xv.x); o.y = f2bf(xv.y); o.z = f2bf(xv.z); o.w = f2bf(xv.w);
    *(ushort4*)(&Xt[r][c]) = o;
  }
  __syncthreads();

  // ---- conv1 for 48 rows: h[t0-8+hr], hr = mt*16 + (quad*4+r), mt=0..2 ----
  {
    floatx4 acc[3][2];
#pragma unroll
    for (int mt = 0; mt < 3; ++mt) { acc[mt][0] = f4zero(); acc[mt][1] = f4zero(); }

#pragma unroll
    for (int tap = 0; tap < 3; ++tap) {
#pragma unroll
      for (int ks = 0; ks < 2; ++ks) {
        shortx8 wf[2];
#pragma unroll
        for (int ct = 0; ct < 2; ++ct) {
          int co = wave * 32 + ct * 16 + l15;
          wf[ct] = *(const shortx8*)(w1t + ((size_t)tap * 128 + co) * 64 + ks * 32 + quad * 8);
        }
#pragma unroll
        for (int mt = 0; mt < 3; ++mt) {
          shortx8 af = *(const shortx8*)(&At[mt * 16 + l15 + tap][ks * 32 + quad * 8]);
          acc[mt][0] = __builtin_amdgcn_mfma_f32_16x16x32_bf16(af, wf[0], acc[mt][0], 0, 0, 0);
          acc[mt][1] = __builtin_amdgcn_mfma_f32_16x16x32_bf16(af, wf[1], acc[mt][1], 0, 0, 0);
        }
      }
    }

#pragma unroll
    for (int ct = 0; ct < 2; ++ct) {
      int co = wave * 32 + ct * 16 + l15;
      float bias = b1[co];
#pragma unroll
      for (int mt = 0; mt < 3; ++mt)
#pragma unroll
        for (int r = 0; r < 4; ++r) {
          int hr = mt * 16 + quad * 4 + r;
          int t = t0 - 8 + hr;
          unsigned short hv = 0;
          if (t >= 0 && t < T_) hv = f2bf(fmaxf(acc[mt][ct][r] + bias, 0.f));
          Ht[hr][co] = hv;
        }
    }
  }
  __syncthreads();

  // ---- conv2 + residual: output rows t0 + mt*16 + quad*4 + r, mt=0..1 ----
  floatx4 a2[2][2], ar[2][2];
#pragma unroll
  for (int mt = 0; mt < 2; ++mt) { a2[mt][0]=f4zero(); a2[mt][1]=f4zero(); ar[mt][0]=f4zero(); ar[mt][1]=f4zero(); }

#pragma unroll
  for (int tap = 0; tap < 3; ++tap) {
#pragma unroll
    for (int ks = 0; ks < 4; ++ks) {
      shortx8 wf[2];
#pragma unroll
      for (int ct = 0; ct < 2; ++ct) {
        int co = wave * 32 + ct * 16 + l15;
        wf[ct] = *(const shortx8*)(w2t + ((size_t)tap * 128 + co) * 128 + ks * 32 + quad * 8);
      }
#pragma unroll
      for (int mt = 0; mt < 2; ++mt) {
        // h[t-1+tap] = Ht[(t-1+tap)-(t0-8)] with t = t0+mt*16+l15 -> row +7+tap
        shortx8 af = *(const shortx8*)(&Ht[mt * 16 + l15 + 7 + tap][ks * 32 + quad * 8]);
        a2[mt][0] = __builtin_amdgcn_mfma_f32_16x16x32_bf16(af, wf[0], a2[mt][0], 0, 0, 0);
        a2[mt][1] = __builtin_amdgcn_mfma_f32_16x16x32_bf16(af, wf[1], a2[mt][1], 0, 0, 0);
      }
    }
  }
#pragma unroll
  for (int ks = 0; ks < 3; ++ks) {
    shortx8 wf[2];
#pragma unroll
    for (int ct = 0; ct < 2; ++ct) {
      int co = wave * 32 + ct * 16 + l15;
      wf[ct] = *(const shortx8*)(dwt + (size_t)co * 96 + ks * 32 + quad * 8);
    }
#pragma unroll
    for (int mt = 0; mt < 2; ++mt) {
      shortx8 af = *(const shortx8*)(&Xt[mt * 16 + l15][ks * 32 + quad * 8]);
      ar[mt][0] = __builtin_amdgcn_mfma_f32_16x16x32_bf16(af, wf[0], ar[mt][0], 0, 0, 0);
      ar[mt][1] = __builtin_amdgcn_mfma_f32_16x16x32_bf16(af, wf[1], ar[mt][1], 0, 0, 0);
    }
  }

  const float kres = 1.0f + 1.0f / 2048.0f;
#pragma unroll
  for (int ct = 0; ct < 2; ++ct) {
    int co = wave * 32 + ct * 16 + l15;
    float bias = b2[co];
#pragma unroll
    for (int mt = 0; mt < 2; ++mt)
#pragma unroll
      for (int r = 0; r < 4; ++r) {
        int t = t0 + mt * 16 + quad * 4 + r;
        float o2 = fmaxf(a2[mt][ct][r] + bias, 0.f);
        out[((size_t)b * T_ + t) * NOUT + co] = fmaxf(o2 + ar[mt][ct][r] * kres, 0.f);
      }
  }
}

// ---------------- launch ----------------
extern "C" void kernel_launch(void* const* d_in, const int* in_sizes, int n_in,
                              void* d_out, int out_size, void* d_ws, size_t ws_size,
                              hipStream_t stream) {
  const float* x      = (const float*)d_in[0];
  const float* qkv_w  = (const float*)d_in[1];
  const float* qkv_b  = (const float*)d_in[2];
  const float* scale  = (const float*)d_in[3];
  const float* cw1    = (const float*)d_in[4];
  const float* cb1    = (const float*)d_in[5];
  const float* cw2    = (const float*)d_in[6];
  const float* cb2    = (const float*)d_in[7];
  const float* dw     = (const float*)d_in[8];

  char* ws = (char*)d_ws;
  unsigned short* qb  = (unsigned short*)(ws + 0);          // [B,T,64]
  unsigned short* kb  = (unsigned short*)(ws + 4194304);    // [B,T,64]
  unsigned short* vT  = (unsigned short*)(ws + 8388608);    // [B,64,T]
  unsigned short* ab  = (unsigned short*)(ws + 12582912);   // [B,T,64]
  unsigned short* qwt = (unsigned short*)(ws + 25165824);   // [192][96]
  unsigned short* w1t = (unsigned short*)(ws + 25202688);   // [3][128][64]
  unsigned short* w2t = (unsigned short*)(ws + 25251840);   // [3][128][128]
  unsigned short* dwt = (unsigned short*)(ws + 25350144);   // [128][96]

  k_wprep <<<408, 256, 0, stream>>>(qkv_w, cw1, cw2, dw, qwt, w1t, w2t, dwt);
  k_qkv   <<<1024, 256, 0, stream>>>(x, qwt, qkv_b, scale, qb, kb, vT);
  k_attn  <<<512, 256, 0, stream>>>(qb, kb, vT, ab);
  k_conv12<<<1024, 256, 0, stream>>>(ab, x, w1t, w2t, dwt, cb1, cb2, (float*)d_out);
}

// Round 13
// 140.543 us; speedup vs baseline: 1.0536x; 1.0536x over previous
//
#include <hip/hip_runtime.h>
#include <cstdint>

#define B_   16
#define T_   2048
#define CIN  96
#define DH   64
#define NOUT 128

typedef float floatx4 __attribute__((ext_vector_type(4)));
typedef short shortx8 __attribute__((ext_vector_type(8)));
typedef unsigned int uintx2 __attribute__((ext_vector_type(2)));

__device__ __forceinline__ unsigned short f2bf(float f) {
  unsigned int u = __float_as_uint(f);
  u += 0x7FFFu + ((u >> 16) & 1u);           // RTNE
  return (unsigned short)(u >> 16);
}
// packed f32x2 -> bf16x2 (RTNE) in one VALU op
__device__ __forceinline__ uint32_t cvtpk(float lo, float hi) {
  uint32_t r;
  asm("v_cvt_pk_bf16_f32 %0, %1, %2" : "=v"(r) : "v"(lo), "v"(hi));
  return r;
}
__device__ __forceinline__ floatx4 f4zero() { floatx4 v; v[0]=0.f;v[1]=0.f;v[2]=0.f;v[3]=0.f; return v; }
__device__ __forceinline__ shortx8 s8zero() { shortx8 v;
#pragma unroll
  for (int i=0;i<8;++i) v[i]=0; return v; }

// swap32 then swap16 between two dwords: redistributes swapped-QK^T P rows
// into the PV A-fragment layout (see k_attn).
__device__ __forceinline__ void plane_swap(uint32_t& a, uint32_t& b) {
#if __has_builtin(__builtin_amdgcn_permlane32_swap) && __has_builtin(__builtin_amdgcn_permlane16_swap)
  uintx2 r1 = __builtin_amdgcn_permlane32_swap(a, b, false, false);
  uintx2 r2 = __builtin_amdgcn_permlane16_swap(r1[0], r1[1], false, false);
  a = r2[0]; b = r2[1];
#else
  asm volatile("v_permlane32_swap_b32 %0, %1\n\t"
               "v_permlane16_swap_b32 %0, %1"
               : "+v"(a), "+v"(b));
#endif
}

// ---------------- k0: weight prep (bf16 + transpose) ----------------
__global__ __launch_bounds__(256) void k_wprep(
    const float* __restrict__ qkv_w, const float* __restrict__ cw1,
    const float* __restrict__ cw2, const float* __restrict__ dw,
    unsigned short* __restrict__ qwt, unsigned short* __restrict__ w1t,
    unsigned short* __restrict__ w2t, unsigned short* __restrict__ dwt)
{
  int o = blockIdx.x * 256 + threadIdx.x;
  if (o < 18432) {
    int co = o / 96, ci = o % 96;
    qwt[o] = f2bf(qkv_w[ci * 192 + co]);
  } else if (o < 43008) {
    int p = o - 18432;
    int tap = p / 8192, rem = p % 8192, co = rem >> 6, ci = rem & 63;
    w1t[p] = f2bf(cw1[(tap * 64 + ci) * 128 + co]);
  } else if (o < 92160) {
    int p = o - 43008;
    int tap = p / 16384, rem = p % 16384, co = rem >> 7, ci = rem & 127;
    w2t[p] = f2bf(cw2[(tap * 128 + ci) * 128 + co]);
  } else if (o < 104448) {
    int p = o - 92160;
    int co = p / 96, ci = p % 96;
    dwt[p] = f2bf(dw[ci * 128 + co]);
  }
}

// ---------------- k1: qkv projection; q pre-scaled by scale*log2(e) ----------------
// V epilogue routes through LDS (Vs) so vT stores are coalesced 16B/lane.
__global__ __launch_bounds__(256) void k_qkv(
    const float* __restrict__ x, const unsigned short* __restrict__ qwt,
    const float* __restrict__ qkv_b, const float* __restrict__ scale_p,
    unsigned short* __restrict__ qb, unsigned short* __restrict__ kb,
    unsigned short* __restrict__ vT)
{
  __shared__ __align__(16) unsigned short Xs[64][104];
  __shared__ __align__(16) unsigned short Vs[64][72];   // [d][t_local]
  const int bx = blockIdx.x;
  const int b = bx >> 5, t0 = (bx & 31) * 64;
  const int tid = threadIdx.x, wave = tid >> 6, lane = tid & 63;
  const int l15 = lane & 15, quad = lane >> 4;
  const float scl2 = scale_p[0] * 1.4426950408889634f;

  for (int idx = tid; idx < 64 * 24; idx += 256) {
    int r = idx / 24, c = (idx % 24) * 4;
    float4 xv = *(const float4*)(x + ((size_t)(b * T_ + t0 + r)) * CIN + c);
    ushort4 o; o.x = f2bf(xv.x); o.y = f2bf(xv.y); o.z = f2bf(xv.z); o.w = f2bf(xv.w);
    *(ushort4*)(&Xs[r][c]) = o;
  }
  __syncthreads();

  floatx4 acc[4][3];
#pragma unroll
  for (int mt = 0; mt < 4; ++mt)
#pragma unroll
    for (int nt = 0; nt < 3; ++nt) acc[mt][nt] = f4zero();

#pragma unroll
  for (int ks = 0; ks < 3; ++ks) {
    shortx8 wf[3];
#pragma unroll
    for (int nt = 0; nt < 3; ++nt) {
      int j = wave * 48 + nt * 16 + l15;
      wf[nt] = *(const shortx8*)(qwt + (size_t)j * 96 + ks * 32 + quad * 8);
    }
#pragma unroll
    for (int mt = 0; mt < 4; ++mt) {
      shortx8 af = *(const shortx8*)(&Xs[mt * 16 + l15][ks * 32 + quad * 8]);
#pragma unroll
      for (int nt = 0; nt < 3; ++nt)
        acc[mt][nt] = __builtin_amdgcn_mfma_f32_16x16x32_bf16(af, wf[nt], acc[mt][nt], 0, 0, 0);
    }
  }

#pragma unroll
  for (int nt = 0; nt < 3; ++nt) {
    int j0 = wave * 48 + nt * 16;
    int j = j0 + l15;
    float bias = qkv_b[j];
#pragma unroll
    for (int mt = 0; mt < 4; ++mt) {
#pragma unroll
      for (int r = 0; r < 4; ++r) {
        int t = t0 + mt * 16 + quad * 4 + r;
        float v = acc[mt][nt][r] + bias;
        if (j0 < 64)        qb[((size_t)b * T_ + t) * DH + j] = f2bf(v * scl2);
        else if (j0 < 128)  kb[((size_t)b * T_ + t) * DH + (j - 64)] = f2bf(v);
        else                Vs[j - 128][mt * 16 + quad * 4 + r] = f2bf(v);
      }
    }
  }
  __syncthreads();
  // coalesced vT write: row d gets 64 consecutive t (128B) via 8 x 16B lanes
  for (int idx = tid; idx < 64 * 8; idx += 256) {
    int d = idx >> 3, seg = (idx & 7) * 8;
    *(shortx8*)(vT + ((size_t)b * DH + d) * T_ + t0 + seg) =
        *(const shortx8*)(&Vs[d][seg]);
  }
}

// ---------------- k2: streaming attention, no-max softmax, full-S ----------------
// 4 waves x 16 queries, one block covers all 32 K/V tiles (no split-S): the
// row-sum (ones-column in V via MFMA) completes in-kernel, so O is normalized
// in registers and written as bf16 ab directly — no fp32 partial round-trip.
// Swapped QK^T keeps P lane-local; v_cvt_pk_bf16_f32 + permlane32/16_swap
// redistribute P to the PV A-fragment with no LDS and minimal VALU.
// XCD swizzle (bijective, 512 = 8 x 64): blocks with the same dispatch-slot
// XCD (bx % 8) get a contiguous wg range = 2 whole batches, so each XCD's L2
// holds only its own 2 batches' K/V -> L2-hit prefetches instead of HBM-miss
// (the prefetch latency sits on the serial path via the pre-barrier vmcnt(0)).
__global__ __launch_bounds__(256) void k_attn(
    const unsigned short* __restrict__ qb, const unsigned short* __restrict__ kb,
    const unsigned short* __restrict__ vT,
    unsigned short* __restrict__ ab)
{
  __shared__ __align__(16) unsigned short Kt[64][72];    // [s][d]
  __shared__ __align__(16) unsigned short Vt[80][72];    // [d][s]; rows 64..79: ones/zeros
  const int bx = blockIdx.x;
  const int wg = ((bx & 7) << 6) | (bx >> 3);            // XCD-contiguous remap
  const int qt = wg & 31, b = wg >> 5;
  const int tid = threadIdx.x, wave = tid >> 6, lane = tid & 63;
  const int l15 = lane & 15, quad = lane >> 4;

  const unsigned short* qrow = qb + ((size_t)b * T_ + qt * 64 + wave * 16 + l15) * DH;
  shortx8 qf0 = *(const shortx8*)(qrow + quad * 8);
  shortx8 qf1 = *(const shortx8*)(qrow + 32 + quad * 8);

  floatx4 O[5];
#pragma unroll
  for (int i = 0; i < 5; ++i) O[i] = f4zero();

  const unsigned short* kbase = kb + (size_t)b * T_ * DH;
  const unsigned short* vbase = vT + (size_t)b * DH * T_;

  // ones-column rows of Vt (d=64 -> 1.0, d=65..79 -> 0), written once
  for (int idx = tid; idx < 16 * 72; idx += 256) {
    int r = idx / 72, c = idx % 72;
    Vt[64 + r][c] = (r == 0) ? (unsigned short)0x3F80 : (unsigned short)0;
  }

  const int kr0 = tid >> 3, kc = (tid & 7) * 8;          // staging coords
  shortx8 pk[2], pv[2];
#pragma unroll
  for (int i = 0; i < 2; ++i) {                          // prefetch tile 0
    pk[i] = *(const shortx8*)(kbase + (size_t)(kr0 + i * 32) * DH + kc);
    pv[i] = *(const shortx8*)(vbase + (size_t)(kr0 + i * 32) * T_ + kc);
  }

  for (int t = 0; t < 32; ++t) {
#pragma unroll
    for (int i = 0; i < 2; ++i) {                        // regs -> LDS
      *(shortx8*)(&Kt[kr0 + i * 32][kc]) = pk[i];
      *(shortx8*)(&Vt[kr0 + i * 32][kc]) = pv[i];
    }
    __syncthreads();                                     // tiles (and ones rows) visible

    if (t < 31) {                                        // prefetch next tile
      int s0 = (t + 1) * 64;
#pragma unroll
      for (int i = 0; i < 2; ++i) {
        pk[i] = *(const shortx8*)(kbase + (size_t)(s0 + kr0 + i * 32) * DH + kc);
        pv[i] = *(const shortx8*)(vbase + (size_t)(kr0 + i * 32) * T_ + s0 + kc);
      }
    }

    // S^T = K.q^T: lane holds S[key=nt*16+quad*4+r][query=l15]
    floatx4 S[4];
#pragma unroll
    for (int nt = 0; nt < 4; ++nt) {
      shortx8 bk0 = *(const shortx8*)(&Kt[nt * 16 + l15][quad * 8]);
      shortx8 bk1 = *(const shortx8*)(&Kt[nt * 16 + l15][32 + quad * 8]);
      S[nt] = f4zero();
      S[nt] = __builtin_amdgcn_mfma_f32_16x16x32_bf16(bk0, qf0, S[nt], 0, 0, 0);
      S[nt] = __builtin_amdgcn_mfma_f32_16x16x32_bf16(bk1, qf1, S[nt], 0, 0, 0);
    }

    // P = exp2(S^T), packed to bf16 pairs via v_cvt_pk_bf16_f32
    uint32_t pkv[8];
#pragma unroll
    for (int nt = 0; nt < 4; ++nt) {
#pragma unroll
      for (int j = 0; j < 2; ++j)
        pkv[nt * 2 + j] = cvtpk(exp2f(S[nt][2 * j]), exp2f(S[nt][2 * j + 1]));
    }

    // Redistribute to PV A-fragment: lane quad q needs keys 32*kk+8q..+7 of
    // query l15. swap32 then swap16 on (ntl=0, ntl=1) reg pairs yields exactly
    // A-frag dwords i=j (from a) and i=j+2 (from b).
#pragma unroll
    for (int kk = 0; kk < 2; ++kk) {
      uint32_t a0 = pkv[4 * kk + 0], b0 = pkv[4 * kk + 2];   // j=0
      plane_swap(a0, b0);
      uint32_t a1 = pkv[4 * kk + 1], b1 = pkv[4 * kk + 3];   // j=1
      plane_swap(a1, b1);
      union { shortx8 s; uint32_t u[4]; } fu;
      fu.u[0] = a0; fu.u[1] = a1; fu.u[2] = b0; fu.u[3] = b1;
#pragma unroll
      for (int dt = 0; dt < 5; ++dt) {
        shortx8 bv = *(const shortx8*)(&Vt[dt * 16 + l15][kk * 32 + quad * 8]);
        O[dt] = __builtin_amdgcn_mfma_f32_16x16x32_bf16(fu.s, bv, O[dt], 0, 0, 0);
      }
    }
    __syncthreads();                                     // K/V consumed before restage
  }

  // normalize in-register and store bf16: lanes l15==0 hold row-sums (col 64)
  unsigned short* abase = ab + ((size_t)b * T_ + qt * 64 + wave * 16) * DH;
#pragma unroll
  for (int r = 0; r < 4; ++r) {
    float s = __shfl(O[4][r], quad << 4);
    float inv = 1.f / s;
    int row = quad * 4 + r;
#pragma unroll
    for (int dt = 0; dt < 4; ++dt)
      abase[(size_t)row * DH + dt * 16 + l15] = f2bf(O[dt][r] * inv);
  }
}

// ---------------- k3: FUSED conv1+relu -> (LDS) -> conv2+relu+residual+relu ----------------
// Block covers 64 output rows. conv1 is computed locally for 80 rows
// (hr=0..79 <-> t=t0-8+hr, 5 MFMA row-tiles) from an 82-row At halo stage,
// rounded through f2bf into LDS Ht — bit-identical to the old hb path.
// Rows with global t outside [0,T) are ZEROED in Ht (conv2 'same' padding needs
// h=0 there, not relu(bias)). Then conv2 + downsample residual as before.
__global__ __launch_bounds__(256) void k_conv12(
    const unsigned short* __restrict__ ab, const float* __restrict__ x,
    const unsigned short* __restrict__ w1t, const unsigned short* __restrict__ w2t,
    const unsigned short* __restrict__ dwt,
    const float* __restrict__ b1, const float* __restrict__ b2,
    float* __restrict__ out)
{
  __shared__ __align__(16) unsigned short At[82][72];    // a rows t0-9 .. t0+72
  __shared__ __align__(16) unsigned short Ht[80][136];   // h rows t0-8 .. t0+71
  __shared__ __align__(16) unsigned short Xt[64][104];
  const int bx = blockIdx.x;
  const int b = bx >> 5, t0 = (bx & 31) * 64;
  const int tid = threadIdx.x, wave = tid >> 6, lane = tid & 63;
  const int l15 = lane & 15, quad = lane >> 4;

  // stage ab with 9/8-row halo: At[ar] <-> t = t0-9+ar
  for (int idx = tid; idx < 82 * 8; idx += 256) {
    int r = idx >> 3, c = (idx & 7) * 8;
    int t = t0 + r - 9;
    shortx8 v = s8zero();
    if (t >= 0 && t < T_) v = *(const shortx8*)(ab + ((size_t)b * T_ + t) * DH + c);
    *(shortx8*)(&At[r][c]) = v;
  }
  // stage x for the residual path
  for (int idx = tid; idx < 64 * 24; idx += 256) {
    int r = idx / 24, c = (idx % 24) * 4;
    float4 xv = *(const float4*)(x + ((size_t)(b * T_ + t0 + r)) * CIN + c);
    ushort4 o; o.x = f2bf(xv.x); o.y = f2bf(xv.y); o.z = f2bf(xv.z); o.w = f2bf(xv.w);
    *(ushort4*)(&Xt[r][c]) = o;
  }
  __syncthreads();

  // ---- conv1 for 80 rows: h[t0-8+hr], hr = mt*16 + (quad*4+r), mt=0..4 ----
  {
    floatx4 acc[5][2];
#pragma unroll
    for (int mt = 0; mt < 5; ++mt) { acc[mt][0] = f4zero(); acc[mt][1] = f4zero(); }

#pragma unroll
    for (int tap = 0; tap < 3; ++tap) {
#pragma unroll
      for (int ks = 0; ks < 2; ++ks) {
        shortx8 wf[2];
#pragma unroll
        for (int ct = 0; ct < 2; ++ct) {
          int co = wave * 32 + ct * 16 + l15;
          wf[ct] = *(const shortx8*)(w1t + ((size_t)tap * 128 + co) * 64 + ks * 32 + quad * 8);
        }
#pragma unroll
        for (int mt = 0; mt < 5; ++mt) {
          shortx8 af = *(const shortx8*)(&At[mt * 16 + l15 + tap][ks * 32 + quad * 8]);
          acc[mt][0] = __builtin_amdgcn_mfma_f32_16x16x32_bf16(af, wf[0], acc[mt][0], 0, 0, 0);
          acc[mt][1] = __builtin_amdgcn_mfma_f32_16x16x32_bf16(af, wf[1], acc[mt][1], 0, 0, 0);
        }
      }
    }

#pragma unroll
    for (int ct = 0; ct < 2; ++ct) {
      int co = wave * 32 + ct * 16 + l15;
      float bias = b1[co];
#pragma unroll
      for (int mt = 0; mt < 5; ++mt)
#pragma unroll
        for (int r = 0; r < 4; ++r) {
          int hr = mt * 16 + quad * 4 + r;
          int t = t0 - 8 + hr;
          unsigned short hv = 0;
          if (t >= 0 && t < T_) hv = f2bf(fmaxf(acc[mt][ct][r] + bias, 0.f));
          Ht[hr][co] = hv;
        }
    }
  }
  __syncthreads();

  // ---- conv2 + residual: output rows t0 + mt*16 + quad*4 + r ----
  floatx4 a2[4][2], ar[4][2];
#pragma unroll
  for (int mt = 0; mt < 4; ++mt) { a2[mt][0]=f4zero(); a2[mt][1]=f4zero(); ar[mt][0]=f4zero(); ar[mt][1]=f4zero(); }

#pragma unroll
  for (int tap = 0; tap < 3; ++tap) {
#pragma unroll
    for (int ks = 0; ks < 4; ++ks) {
      shortx8 wf[2];
#pragma unroll
      for (int ct = 0; ct < 2; ++ct) {
        int co = wave * 32 + ct * 16 + l15;
        wf[ct] = *(const shortx8*)(w2t + ((size_t)tap * 128 + co) * 128 + ks * 32 + quad * 8);
      }
#pragma unroll
      for (int mt = 0; mt < 4; ++mt) {
        // h[t-1+tap] = Ht[(t-1+tap)-(t0-8)] with t = t0+mt*16+l15 -> row +7+tap
        shortx8 af = *(const shortx8*)(&Ht[mt * 16 + l15 + 7 + tap][ks * 32 + quad * 8]);
        a2[mt][0] = __builtin_amdgcn_mfma_f32_16x16x32_bf16(af, wf[0], a2[mt][0], 0, 0, 0);
        a2[mt][1] = __builtin_amdgcn_mfma_f32_16x16x32_bf16(af, wf[1], a2[mt][1], 0, 0, 0);
      }
    }
  }
#pragma unroll
  for (int ks = 0; ks < 3; ++ks) {
    shortx8 wf[2];
#pragma unroll
    for (int ct = 0; ct < 2; ++ct) {
      int co = wave * 32 + ct * 16 + l15;
      wf[ct] = *(const shortx8*)(dwt + (size_t)co * 96 + ks * 32 + quad * 8);
    }
#pragma unroll
    for (int mt = 0; mt < 4; ++mt) {
      shortx8 af = *(const shortx8*)(&Xt[mt * 16 + l15][ks * 32 + quad * 8]);
      ar[mt][0] = __builtin_amdgcn_mfma_f32_16x16x32_bf16(af, wf[0], ar[mt][0], 0, 0, 0);
      ar[mt][1] = __builtin_amdgcn_mfma_f32_16x16x32_bf16(af, wf[1], ar[mt][1], 0, 0, 0);
    }
  }

  const float kres = 1.0f + 1.0f / 2048.0f;
#pragma unroll
  for (int ct = 0; ct < 2; ++ct) {
    int co = wave * 32 + ct * 16 + l15;
    float bias = b2[co];
#pragma unroll
    for (int mt = 0; mt < 4; ++mt)
#pragma unroll
      for (int r = 0; r < 4; ++r) {
        int t = t0 + mt * 16 + quad * 4 + r;
        float o2 = fmaxf(a2[mt][ct][r] + bias, 0.f);
        out[((size_t)b * T_ + t) * NOUT + co] = fmaxf(o2 + ar[mt][ct][r] * kres, 0.f);
      }
  }
}

// ---------------- launch ----------------
extern "C" void kernel_launch(void* const* d_in, const int* in_sizes, int n_in,
                              void* d_out, int out_size, void* d_ws, size_t ws_size,
                              hipStream_t stream) {
  const float* x      = (const float*)d_in[0];
  const float* qkv_w  = (const float*)d_in[1];
  const float* qkv_b  = (const float*)d_in[2];
  const float* scale  = (const float*)d_in[3];
  const float* cw1    = (const float*)d_in[4];
  const float* cb1    = (const float*)d_in[5];
  const float* cw2    = (const float*)d_in[6];
  const float* cb2    = (const float*)d_in[7];
  const float* dw     = (const float*)d_in[8];

  char* ws = (char*)d_ws;
  unsigned short* qb  = (unsigned short*)(ws + 0);          // [B,T,64]
  unsigned short* kb  = (unsigned short*)(ws + 4194304);    // [B,T,64]
  unsigned short* vT  = (unsigned short*)(ws + 8388608);    // [B,64,T]
  unsigned short* ab  = (unsigned short*)(ws + 12582912);   // [B,T,64]
  unsigned short* qwt = (unsigned short*)(ws + 25165824);   // [192][96]
  unsigned short* w1t = (unsigned short*)(ws + 25202688);   // [3][128][64]
  unsigned short* w2t = (unsigned short*)(ws + 25251840);   // [3][128][128]
  unsigned short* dwt = (unsigned short*)(ws + 25350144);   // [128][96]

  k_wprep <<<408, 256, 0, stream>>>(qkv_w, cw1, cw2, dw, qwt, w1t, w2t, dwt);
  k_qkv   <<<512, 256, 0, stream>>>(x, qwt, qkv_b, scale, qb, kb, vT);
  k_attn  <<<512, 256, 0, stream>>>(qb, kb, vT, ab);
  k_conv12<<<512, 256, 0, stream>>>(ab, x, w1t, w2t, dwt, cb1, cb2, (float*)d_out);
}